// Round 1
// baseline (347.987 us; speedup 1.0000x reference)
//
#include <hip/hip_runtime.h>
#include <cstdint>
#include <cstddef>

#define NV 6
#define ND 256
#define NHEAD 8
#define NDH 32
#define NL 4
#define NZP 4
#define NBEV 80
#define NQ 6400
#define NTOK 7441
#define MROWS (NV * NTOK)
#define FEPS 1e-5f

// level geometry
__device__ __constant__ const int c_lw[4] = {100, 50, 25, 13};
__device__ __constant__ const int c_lh[4] = {56, 28, 14, 7};
__device__ __constant__ const int c_lst[4] = {0, 5600, 7000, 7350};

// ---------------------------------------------------------------------------
// K1: project BEV pillar centers through lidar2img; all ZP points identical
// (reference z-overwrite bug), so one coord/mask per (v,q).
// ---------------------------------------------------------------------------
__global__ void k_proj(const float* __restrict__ l2i,
                       float2* __restrict__ coords, int* __restrict__ mask) {
    int idx = blockIdx.x * blockDim.x + threadIdx.x;
    if (idx >= NV * NQ) return;
    int v = idx / NQ, q = idx - v * NQ;
    float xs = ((float)(q % NBEV) + 0.5f) / (float)NBEV;
    float ys = ((float)(q / NBEV) + 0.5f) / (float)NBEV;
    float x = xs * 96.0f - 48.0f;
    float y = ys * 96.0f - 48.0f;
    float z = x * 8.0f - 5.0f;           // faithful reproduction of ref bug
    const float* M = l2i + v * 16;
    float ip0 = M[0] * x + M[1] * y + M[2] * z + M[3];
    float ip1 = M[4] * x + M[5] * y + M[6] * z + M[7];
    float ip2 = M[8] * x + M[9] * y + M[10] * z + M[11];
    float dz = fmaxf(ip2, FEPS);
    float xn = ip0 / dz / 800.0f;
    float yn = ip1 / dz / 448.0f;
    bool m = (ip2 > FEPS) && (xn > 0.0f) && (xn < 1.0f) && (yn > 0.0f) && (yn < 1.0f);
    coords[idx] = make_float2(xn, yn);
    mask[idx] = m ? 1 : 0;
}

// ---------------------------------------------------------------------------
// K2: emb_proj[v*4+l][c] = (view_emb[v] + level_emb[l]) @ value_W + value_b
// 24 rows only; folded into the value GEMM epilogue.
// ---------------------------------------------------------------------------
__global__ void k_embproj(const float* __restrict__ ve, const float* __restrict__ le,
                          const float* __restrict__ W, const float* __restrict__ b,
                          float* __restrict__ emb_proj) {
    int blk = blockIdx.x;             // v*4 + l
    int v = blk >> 2, l = blk & 3;
    int c = threadIdx.x;
    float acc = b[c];
    for (int d = 0; d < ND; ++d)
        acc += (ve[v * ND + d] + le[l * ND + d]) * W[d * ND + c];
    emb_proj[blk * ND + c] = acc;
}

// ---------------------------------------------------------------------------
// K3: off = bev_emb @ off_W + off_b ; aw = softmax16(bev_emb @ aw_W + aw_b)
// 8 queries per 384-thread block (threads 0..255 -> off cols, 256..383 -> aw).
// ---------------------------------------------------------------------------
#define QB_OA 8
__global__ __launch_bounds__(384) void k_offaw(
        const float* __restrict__ bev,
        const float* __restrict__ offW, const float* __restrict__ offB,
        const float* __restrict__ awW, const float* __restrict__ awB,
        float* __restrict__ off, float* __restrict__ aw) {
    __shared__ float emb_s[QB_OA][ND];
    __shared__ float aw_l[QB_OA][128];
    int t = threadIdx.x;
    int q0 = blockIdx.x * QB_OA;
    for (int i = t; i < QB_OA * ND; i += 384) {
        int qq = i >> 8, d = i & 255;
        emb_s[qq][d] = bev[(size_t)(q0 + qq) * ND + d];
    }
    __syncthreads();
    if (t < 256) {
        float acc[QB_OA];
#pragma unroll
        for (int qq = 0; qq < QB_OA; ++qq) acc[qq] = 0.0f;
        for (int d = 0; d < ND; d += 4) {
            float w0 = offW[(d + 0) * 256 + t];
            float w1 = offW[(d + 1) * 256 + t];
            float w2 = offW[(d + 2) * 256 + t];
            float w3 = offW[(d + 3) * 256 + t];
#pragma unroll
            for (int qq = 0; qq < QB_OA; ++qq) {
                float4 e = *(const float4*)&emb_s[qq][d];
                acc[qq] += e.x * w0 + e.y * w1 + e.z * w2 + e.w * w3;
            }
        }
        float bb = offB[t];
#pragma unroll
        for (int qq = 0; qq < QB_OA; ++qq)
            off[(size_t)(q0 + qq) * 256 + t] = acc[qq] + bb;
    } else {
        int c = t - 256;  // 0..127
        float acc[QB_OA];
#pragma unroll
        for (int qq = 0; qq < QB_OA; ++qq) acc[qq] = 0.0f;
        for (int d = 0; d < ND; d += 4) {
            float w0 = awW[(d + 0) * 128 + c];
            float w1 = awW[(d + 1) * 128 + c];
            float w2 = awW[(d + 2) * 128 + c];
            float w3 = awW[(d + 3) * 128 + c];
#pragma unroll
            for (int qq = 0; qq < QB_OA; ++qq) {
                float4 e = *(const float4*)&emb_s[qq][d];
                acc[qq] += e.x * w0 + e.y * w1 + e.z * w2 + e.w * w3;
            }
        }
        float bb = awB[c];
#pragma unroll
        for (int qq = 0; qq < QB_OA; ++qq) aw_l[qq][c] = acc[qq] + bb;
    }
    __syncthreads();
    if (t < QB_OA * NHEAD) {  // 64 threads: one (qq, head) each
        int qq = t >> 3, h = t & 7;
        float mx = -1e30f;
        for (int i = 0; i < 16; ++i) mx = fmaxf(mx, aw_l[qq][h * 16 + i]);
        float e[16];
        float s = 0.0f;
        for (int i = 0; i < 16; ++i) {
            e[i] = expf(aw_l[qq][h * 16 + i] - mx);
            s += e[i];
        }
        float inv = 1.0f / s;
        for (int i = 0; i < 16; ++i)
            aw[(size_t)(q0 + qq) * 128 + h * 16 + i] = e[i] * inv;
    }
}

// ---------------------------------------------------------------------------
// K4: value GEMM. value[v*N+n][c] = sum_d feat_l[v][d][p] * W[d][c] + emb_proj.
// 64x64 tile, 256 threads, 4x4 micro-tile, K-chunk 16. A rows gathered via
// per-row (base ptr, stride=hw) since feats are channels-first per level.
// ---------------------------------------------------------------------------
__global__ __launch_bounds__(256) void k_value(
        const float* __restrict__ f0, const float* __restrict__ f1,
        const float* __restrict__ f2, const float* __restrict__ f3,
        const float* __restrict__ W, const float* __restrict__ emb_proj,
        float* __restrict__ value) {
    __shared__ float As[16][64];
    __shared__ float Bs[16][64];
    __shared__ const float* rowptr[64];
    __shared__ int rowstride[64];
    __shared__ int rowemb[64];
    int t = threadIdx.x;
    int m0 = blockIdx.x * 64;
    int c0 = blockIdx.y * 64;
    if (t < 64) {
        int m = m0 + t;
        if (m >= MROWS) m = MROWS - 1;
        int v = m / NTOK, n = m - v * NTOK;
        int l, p, hw;
        const float* base;
        if (n < 5600)      { l = 0; p = n;        hw = 5600; base = f0; }
        else if (n < 7000) { l = 1; p = n - 5600; hw = 1400; base = f1; }
        else if (n < 7350) { l = 2; p = n - 7000; hw = 350;  base = f2; }
        else               { l = 3; p = n - 7350; hw = 91;   base = f3; }
        rowptr[t] = base + (size_t)v * ND * hw + p;
        rowstride[t] = hw;
        rowemb[t] = v * 4 + l;
    }
    __syncthreads();
    int r = t & 63, kk = t >> 6;   // loader role
    int tr = t >> 4, tc = t & 15;  // compute role: rows tr*4.., cols tc*4..
    float acc[4][4];
#pragma unroll
    for (int i = 0; i < 4; ++i)
#pragma unroll
        for (int j = 0; j < 4; ++j) acc[i][j] = 0.0f;

    const float* rp = rowptr[r];
    int rs = rowstride[r];
    for (int k0 = 0; k0 < ND; k0 += 16) {
#pragma unroll
        for (int i = 0; i < 4; ++i) {
            int k = kk + i * 4;
            As[k][r] = rp[(size_t)(k0 + k) * rs];
            Bs[k][r] = W[(size_t)(k0 + k) * ND + c0 + r];
        }
        __syncthreads();
#pragma unroll
        for (int k = 0; k < 16; ++k) {
            float4 a4 = *(const float4*)&As[k][tr * 4];
            float4 b4 = *(const float4*)&Bs[k][tc * 4];
            float av[4] = {a4.x, a4.y, a4.z, a4.w};
            float bv[4] = {b4.x, b4.y, b4.z, b4.w};
#pragma unroll
            for (int i = 0; i < 4; ++i)
#pragma unroll
                for (int j = 0; j < 4; ++j) acc[i][j] += av[i] * bv[j];
        }
        __syncthreads();
    }
#pragma unroll
    for (int i = 0; i < 4; ++i) {
        int m = m0 + tr * 4 + i;
        if (m < MROWS) {
            int ei = rowemb[tr * 4 + i];
            float4 e = *(const float4*)&emb_proj[(size_t)ei * ND + c0 + tc * 4];
            float4 o;
            o.x = acc[i][0] + e.x;
            o.y = acc[i][1] + e.y;
            o.z = acc[i][2] + e.z;
            o.w = acc[i][3] + e.w;
            *(float4*)&value[(size_t)m * ND + c0 + tc * 4] = o;
        }
    }
}

// ---------------------------------------------------------------------------
// K5: fused sampler + masked view-mean + out GEMM + residual.
// Block = 256 threads handles 8 queries. Thread t -> (head=t>>5, dh=t&31),
// channel c = t. Skips masked (v,q) entirely (exact: attn*0 = 0).
// ---------------------------------------------------------------------------
#define QB 8
__global__ __launch_bounds__(256) void k_main(
        const float2* __restrict__ coords, const int* __restrict__ mask,
        const float* __restrict__ off, const float* __restrict__ aw,
        const float* __restrict__ value, const float* __restrict__ bev,
        const float* __restrict__ outW, const float* __restrict__ outB,
        float* __restrict__ out) {
    __shared__ float off_s[QB][256];
    __shared__ float aw_s[QB][128];
    __shared__ float slots_s[QB][256];
    __shared__ float2 cxy_s[QB][NV];
    __shared__ int msk_s[QB][NV];
    __shared__ int wx0[128], wy0[128];
    __shared__ float wfx[128], wfy[128], wa[128];

    int t = threadIdx.x;
    int q0 = blockIdx.x * QB;
#pragma unroll
    for (int qq = 0; qq < QB; ++qq) {
        off_s[qq][t] = off[(size_t)(q0 + qq) * 256 + t];
        if (t < 128) aw_s[qq][t] = aw[(size_t)(q0 + qq) * 128 + t];
    }
    if (t < QB * NV) {
        int qq = t / NV, v = t - qq * NV;
        msk_s[qq][v] = mask[v * NQ + q0 + qq];
        cxy_s[qq][v] = coords[v * NQ + q0 + qq];
    }
    __syncthreads();

    int h = t >> 5, dh = t & 31;
    for (int qq = 0; qq < QB; ++qq) {
        float acc = 0.0f;
        int cnt = 0;
#pragma unroll
        for (int v = 0; v < NV; ++v) cnt += msk_s[qq][v];
        for (int v = 0; v < NV; ++v) {
            if (!msk_s[qq][v]) continue;  // uniform branch (LDS value)
            if (t < 128) {
                // t = hh*16 + ll*4 + zz  (combo index)
                int ll = (t >> 2) & 3;
                float wl = (float)c_lw[ll], hl = (float)c_lh[ll];
                float ox = off_s[qq][2 * t];
                float oy = off_s[qq][2 * t + 1];
                float2 c = cxy_s[qq][v];
                float gx = (c.x + ox / wl) * wl - 0.5f;
                float gy = (c.y + oy / hl) * hl - 0.5f;
                float fx = floorf(gx), fy = floorf(gy);
                wx0[t] = (int)fx;
                wy0[t] = (int)fy;
                wfx[t] = gx - fx;
                wfy[t] = gy - fy;
                wa[t] = aw_s[qq][t];
            }
            __syncthreads();
            const float* vb = value + ((size_t)v * NTOK) * 256 + h * 32 + dh;
            for (int ci = 0; ci < 16; ++ci) {
                int c2 = h * 16 + ci;
                int ll = ci >> 2;
                int wl = c_lw[ll], hl = c_lh[ll], st = c_lst[ll];
                int x0 = wx0[c2], y0 = wy0[c2];
                float wx = wfx[c2], wy = wfy[c2];
                float s = 0.0f;
                if ((unsigned)y0 < (unsigned)hl) {
                    int row = st + y0 * wl;
                    if ((unsigned)x0 < (unsigned)wl)
                        s += (1.0f - wx) * (1.0f - wy) * vb[(size_t)(row + x0) * 256];
                    if ((unsigned)(x0 + 1) < (unsigned)wl)
                        s += wx * (1.0f - wy) * vb[(size_t)(row + x0 + 1) * 256];
                }
                if ((unsigned)(y0 + 1) < (unsigned)hl) {
                    int row = st + (y0 + 1) * wl;
                    if ((unsigned)x0 < (unsigned)wl)
                        s += (1.0f - wx) * wy * vb[(size_t)(row + x0) * 256];
                    if ((unsigned)(x0 + 1) < (unsigned)wl)
                        s += wx * wy * vb[(size_t)(row + x0 + 1) * 256];
                }
                acc += wa[c2] * s;
            }
            __syncthreads();
        }
        float invc = 1.0f / fmaxf((float)cnt, 1.0f);
        slots_s[qq][t] = acc * invc;
    }
    __syncthreads();

    // out GEMM: y[qq][t] = bev + out_b + sum_d slots[qq][d] * outW[d][t]
    float y[QB];
    float ob = outB[t];
#pragma unroll
    for (int qq = 0; qq < QB; ++qq)
        y[qq] = ob + bev[(size_t)(q0 + qq) * 256 + t];
    for (int d = 0; d < 256; d += 4) {
        float w0 = outW[(size_t)(d + 0) * 256 + t];
        float w1 = outW[(size_t)(d + 1) * 256 + t];
        float w2 = outW[(size_t)(d + 2) * 256 + t];
        float w3 = outW[(size_t)(d + 3) * 256 + t];
#pragma unroll
        for (int qq = 0; qq < QB; ++qq) {
            float4 s4 = *(const float4*)&slots_s[qq][d];
            y[qq] += s4.x * w0 + s4.y * w1 + s4.z * w2 + s4.w * w3;
        }
    }
#pragma unroll
    for (int qq = 0; qq < QB; ++qq)
        out[(size_t)(q0 + qq) * 256 + t] = y[qq];
}

// ---------------------------------------------------------------------------
extern "C" void kernel_launch(void* const* d_in, const int* in_sizes, int n_in,
                              void* d_out, int out_size, void* d_ws, size_t ws_size,
                              hipStream_t stream) {
    const float* f0   = (const float*)d_in[0];
    const float* f1   = (const float*)d_in[1];
    const float* f2   = (const float*)d_in[2];
    const float* f3   = (const float*)d_in[3];
    const float* l2i  = (const float*)d_in[4];
    const float* bev  = (const float*)d_in[5];
    const float* le   = (const float*)d_in[6];
    const float* ve   = (const float*)d_in[7];
    const float* vW   = (const float*)d_in[8];
    const float* vB   = (const float*)d_in[9];
    const float* oW   = (const float*)d_in[10];
    const float* oB   = (const float*)d_in[11];
    const float* aW   = (const float*)d_in[12];
    const float* aB   = (const float*)d_in[13];
    const float* outW = (const float*)d_in[14];
    const float* outB = (const float*)d_in[15];
    float* out = (float*)d_out;

    char* ws = (char*)d_ws;
    size_t o = 0;
    auto alloc = [&](size_t bytes) {
        void* p = ws + o;
        o += (bytes + 255) & ~(size_t)255;
        return p;
    };
    float2* coords   = (float2*)alloc((size_t)NV * NQ * sizeof(float2));
    int*    mask     = (int*)alloc((size_t)NV * NQ * sizeof(int));
    float*  emb_proj = (float*)alloc((size_t)24 * ND * sizeof(float));
    float*  off      = (float*)alloc((size_t)NQ * 256 * sizeof(float));
    float*  aw       = (float*)alloc((size_t)NQ * 128 * sizeof(float));
    float*  value    = (float*)alloc((size_t)MROWS * ND * sizeof(float));

    k_proj<<<(NV * NQ + 255) / 256, 256, 0, stream>>>(l2i, coords, mask);
    k_embproj<<<24, 256, 0, stream>>>(ve, le, vW, vB, emb_proj);
    k_offaw<<<NQ / QB_OA, 384, 0, stream>>>(bev, oW, oB, aW, aB, off, aw);
    dim3 gv((MROWS + 63) / 64, 4);
    k_value<<<gv, 256, 0, stream>>>(f0, f1, f2, f3, vW, emb_proj, value);
    k_main<<<NQ / QB, 256, 0, stream>>>(coords, mask, off, aw, value, bev, outW, outB, out);
}

// Round 2
// 250.449 us; speedup vs baseline: 1.3895x; 1.3895x over previous
//
#include <hip/hip_runtime.h>
#include <cstdint>
#include <cstddef>

#define NV 6
#define ND 256
#define NHEAD 8
#define NL 4
#define NBEV 80
#define NQ 6400
#define NTOK 7441
#define MROWS (NV * NTOK)
#define FEPS 1e-5f

typedef __attribute__((ext_vector_type(8))) short bfx8;
typedef __attribute__((ext_vector_type(4))) float fx4;

__device__ __forceinline__ unsigned short f2bf(float x) {
    uint32_t u = __builtin_bit_cast(uint32_t, x);
    u += 0x7FFFu + ((u >> 16) & 1u);
    return (unsigned short)(u >> 16);
}
__device__ __forceinline__ float bf2f(unsigned short b) {
    uint32_t u = ((uint32_t)b) << 16;
    return __builtin_bit_cast(float, u);
}

// ---------------------------------------------------------------------------
// K1: project BEV pillar centers; one coord/mask per (v,q) (ZP collapse).
// ---------------------------------------------------------------------------
__global__ void k_proj(const float* __restrict__ l2i,
                       float2* __restrict__ coords, int* __restrict__ mask) {
    int idx = blockIdx.x * blockDim.x + threadIdx.x;
    if (idx >= NV * NQ) return;
    int v = idx / NQ, q = idx - v * NQ;
    float xs = ((float)(q % NBEV) + 0.5f) / (float)NBEV;
    float ys = ((float)(q / NBEV) + 0.5f) / (float)NBEV;
    float x = xs * 96.0f - 48.0f;
    float y = ys * 96.0f - 48.0f;
    float z = x * 8.0f - 5.0f;  // faithful ref bug
    const float* M = l2i + v * 16;
    float ip0 = M[0] * x + M[1] * y + M[2] * z + M[3];
    float ip1 = M[4] * x + M[5] * y + M[6] * z + M[7];
    float ip2 = M[8] * x + M[9] * y + M[10] * z + M[11];
    float dz = fmaxf(ip2, FEPS);
    float xn = ip0 / dz / 800.0f;
    float yn = ip1 / dz / 448.0f;
    bool m = (ip2 > FEPS) && (xn > 0.0f) && (xn < 1.0f) && (yn > 0.0f) && (yn < 1.0f);
    coords[idx] = make_float2(xn, yn);
    mask[idx] = m ? 1 : 0;
}

// ---------------------------------------------------------------------------
// K2: emb_proj[v*4+l][c] = (view_emb[v]+level_emb[l]) @ value_W + value_b (f32)
// ---------------------------------------------------------------------------
__global__ void k_embproj(const float* __restrict__ ve, const float* __restrict__ le,
                          const float* __restrict__ W, const float* __restrict__ b,
                          float* __restrict__ emb_proj) {
    int blk = blockIdx.x;  // v*4 + l
    int v = blk >> 2, l = blk & 3;
    int c = threadIdx.x;
    float acc = b[c];
    for (int d = 0; d < ND; ++d)
        acc += (ve[v * ND + d] + le[l * ND + d]) * W[d * ND + c];
    emb_proj[blk * ND + c] = acc;
}

// ---------------------------------------------------------------------------
// K3: Wt[n][k] = bf16(W[k][n]); K fixed 256, N param.
// ---------------------------------------------------------------------------
__global__ void k_transpose(const float* __restrict__ W, unsigned short* __restrict__ Wt,
                            int N) {
    int idx = blockIdx.x * blockDim.x + threadIdx.x;
    if (idx >= N * 256) return;
    int k = idx & 255, n = idx >> 8;
    Wt[(size_t)n * 256 + k] = f2bf(W[(size_t)k * N + n]);
}

// ---------------------------------------------------------------------------
// K4: generic MFMA GEMM: out[M][N] = A[M][256] @ Bt^T + bias (+ addsrc).
// A row-major f32 (lda), Bt = [N][256] bf16. M % 128 == 0. Tile 128x128.
// ---------------------------------------------------------------------------
__global__ __launch_bounds__(256) void k_gemm(
        const float* __restrict__ A, int lda,
        const unsigned short* __restrict__ Bt,
        const float* __restrict__ bias, const float* __restrict__ addsrc,
        float* __restrict__ out, int N) {
    __shared__ unsigned short As[128][40];
    __shared__ unsigned short Bs[128][40];
    int t = threadIdx.x;
    int m0 = blockIdx.x * 128, c0 = blockIdx.y * 128;
    int lane = t & 63, w = t >> 6;
    int wm = w >> 1, wn = w & 1;
    int lr = lane & 15, lk = lane >> 4;

    const float* ap = A + (size_t)(m0 + (t >> 1)) * lda + (t & 1) * 16;
    const unsigned short* bp = Bt + (size_t)(c0 + (t >> 1)) * 256 + (t & 1) * 16;
    int sr = t >> 1, sc = (t & 1) * 16;

    fx4 acc[4][4];
#pragma unroll
    for (int i = 0; i < 4; ++i)
#pragma unroll
        for (int j = 0; j < 4; ++j) acc[i][j] = (fx4)0.0f;

    for (int k0 = 0; k0 < 256; k0 += 32) {
        float va[16];
#pragma unroll
        for (int i = 0; i < 4; ++i)
            *(float4*)&va[i * 4] = *(const float4*)(ap + k0 + i * 4);
        bfx8 lo, hi;
#pragma unroll
        for (int i = 0; i < 8; ++i) {
            lo[i] = (short)f2bf(va[i]);
            hi[i] = (short)f2bf(va[i + 8]);
        }
        *(bfx8*)&As[sr][sc] = lo;
        *(bfx8*)&As[sr][sc + 8] = hi;
        *(bfx8*)&Bs[sr][sc] = *(const bfx8*)(bp + k0);
        *(bfx8*)&Bs[sr][sc + 8] = *(const bfx8*)(bp + k0 + 8);
        __syncthreads();
        bfx8 af[4], bf[4];
#pragma unroll
        for (int f = 0; f < 4; ++f) {
            af[f] = *(bfx8*)&As[wm * 64 + f * 16 + lr][lk * 8];
            bf[f] = *(bfx8*)&Bs[wn * 64 + f * 16 + lr][lk * 8];
        }
#pragma unroll
        for (int fm = 0; fm < 4; ++fm)
#pragma unroll
            for (int fn = 0; fn < 4; ++fn)
                acc[fm][fn] = __builtin_amdgcn_mfma_f32_16x16x32_bf16(
                    af[fm], bf[fn], acc[fm][fn], 0, 0, 0);
        __syncthreads();
    }
#pragma unroll
    for (int fm = 0; fm < 4; ++fm) {
#pragma unroll
        for (int fn = 0; fn < 4; ++fn) {
            int col = c0 + wn * 64 + fn * 16 + lr;
            float bs = bias[col];
#pragma unroll
            for (int r = 0; r < 4; ++r) {
                int m = m0 + wm * 64 + fm * 16 + lk * 4 + r;
                float vv = acc[fm][fn][r] + bs;
                if (addsrc) vv += addsrc[(size_t)m * N + col];
                out[(size_t)m * N + col] = vv;
            }
        }
    }
}

// ---------------------------------------------------------------------------
// K5: value GEMM (gathered A rows from channels-first feats) -> bf16 value,
// + emb_proj epilogue. Same MFMA structure as k_gemm.
// ---------------------------------------------------------------------------
__global__ __launch_bounds__(256) void k_value_gemm(
        const float* __restrict__ f0, const float* __restrict__ f1,
        const float* __restrict__ f2, const float* __restrict__ f3,
        const unsigned short* __restrict__ Wt, const float* __restrict__ emb_proj,
        unsigned short* __restrict__ value) {
    __shared__ unsigned short As[128][40];
    __shared__ unsigned short Bs[128][40];
    __shared__ const float* rowptr[128];
    __shared__ int rowstride[128];
    __shared__ int rowemb[128];
    int t = threadIdx.x;
    int m0 = blockIdx.x * 128, c0 = blockIdx.y * 128;
    if (t < 128) {
        int m = m0 + t;
        if (m >= MROWS) m = MROWS - 1;
        int v = m / NTOK, n = m - v * NTOK;
        int l, p, hw;
        const float* base;
        if (n < 5600)      { l = 0; p = n;        hw = 5600; base = f0; }
        else if (n < 7000) { l = 1; p = n - 5600; hw = 1400; base = f1; }
        else if (n < 7350) { l = 2; p = n - 7000; hw = 350;  base = f2; }
        else               { l = 3; p = n - 7350; hw = 91;   base = f3; }
        rowptr[t] = base + (size_t)v * ND * hw + p;
        rowstride[t] = hw;
        rowemb[t] = v * 4 + l;
    }
    __syncthreads();

    int lane = t & 63, w = t >> 6;
    int wm = w >> 1, wn = w & 1;
    int lr = lane & 15, lk = lane >> 4;
    int mA = t & 127, kg = t >> 7;               // A staging role
    const unsigned short* bp = Wt + (size_t)(c0 + (t >> 1)) * 256 + (t & 1) * 16;
    int br = t >> 1, bc = (t & 1) * 16;

    const float* rp = rowptr[mA];
    int rs = rowstride[mA];

    fx4 acc[4][4];
#pragma unroll
    for (int i = 0; i < 4; ++i)
#pragma unroll
        for (int j = 0; j < 4; ++j) acc[i][j] = (fx4)0.0f;

    for (int k0 = 0; k0 < 256; k0 += 32) {
        float va[16];
#pragma unroll
        for (int i = 0; i < 16; ++i)
            va[i] = rp[(size_t)(k0 + kg * 16 + i) * rs];
        bfx8 lo, hi;
#pragma unroll
        for (int i = 0; i < 8; ++i) {
            lo[i] = (short)f2bf(va[i]);
            hi[i] = (short)f2bf(va[i + 8]);
        }
        *(bfx8*)&As[mA][kg * 16] = lo;
        *(bfx8*)&As[mA][kg * 16 + 8] = hi;
        *(bfx8*)&Bs[br][bc] = *(const bfx8*)(bp + k0);
        *(bfx8*)&Bs[br][bc + 8] = *(const bfx8*)(bp + k0 + 8);
        __syncthreads();
        bfx8 af[4], bf[4];
#pragma unroll
        for (int f = 0; f < 4; ++f) {
            af[f] = *(bfx8*)&As[wm * 64 + f * 16 + lr][lk * 8];
            bf[f] = *(bfx8*)&Bs[wn * 64 + f * 16 + lr][lk * 8];
        }
#pragma unroll
        for (int fm = 0; fm < 4; ++fm)
#pragma unroll
            for (int fn = 0; fn < 4; ++fn)
                acc[fm][fn] = __builtin_amdgcn_mfma_f32_16x16x32_bf16(
                    af[fm], bf[fn], acc[fm][fn], 0, 0, 0);
        __syncthreads();
    }
#pragma unroll
    for (int fm = 0; fm < 4; ++fm) {
#pragma unroll
        for (int fn = 0; fn < 4; ++fn) {
            int col = c0 + wn * 64 + fn * 16 + lr;
#pragma unroll
            for (int r = 0; r < 4; ++r) {
                int rl = wm * 64 + fm * 16 + lk * 4 + r;
                int m = m0 + rl;
                if (m < MROWS) {
                    float e = emb_proj[(size_t)rowemb[rl] * ND + col];
                    value[(size_t)m * ND + col] = f2bf(acc[fm][fn][r] + e);
                }
            }
        }
    }
}

// ---------------------------------------------------------------------------
// K6: per-(q,head) softmax over 16 logits.
// ---------------------------------------------------------------------------
__global__ void k_softmax(const float* __restrict__ pre, float* __restrict__ aw) {
    int idx = blockIdx.x * blockDim.x + threadIdx.x;
    if (idx >= NQ * NHEAD) return;
    int q = idx >> 3, h = idx & 7;
    const float* p = pre + (size_t)q * 128 + h * 16;
    float v[16];
#pragma unroll
    for (int i = 0; i < 4; ++i) *(float4*)&v[i * 4] = *(const float4*)(p + i * 4);
    float mx = -1e30f;
#pragma unroll
    for (int i = 0; i < 16; ++i) mx = fmaxf(mx, v[i]);
    float s = 0.0f;
#pragma unroll
    for (int i = 0; i < 16; ++i) { v[i] = expf(v[i] - mx); s += v[i]; }
    float inv = 1.0f / s;
    float* o = aw + (size_t)q * 128 + h * 16;
#pragma unroll
    for (int i = 0; i < 16; ++i) o[i] = v[i] * inv;
}

// ---------------------------------------------------------------------------
// K7: sampler. 2 queries/block, one barrier, branch-free clamped corners,
// bf16 value, writes slots (f32).
// ---------------------------------------------------------------------------
#define SQB 2
__global__ __launch_bounds__(256) void k_sample(
        const float2* __restrict__ coords, const int* __restrict__ mask,
        const float* __restrict__ off, const float* __restrict__ aw,
        const unsigned short* __restrict__ value, float* __restrict__ slots) {
    __shared__ float aw_s[SQB][128];
    __shared__ int pxy_s[SQB][NV][128];
    __shared__ float2 wxy_s[SQB][NV][128];
    __shared__ float2 cxy_s[SQB][NV];
    __shared__ int msk_s[SQB][NV];

    int t = threadIdx.x;
    int q0 = blockIdx.x * SQB;
    if (t < SQB * NV) {
        int qq = t / NV, v = t - qq * NV;
        msk_s[qq][v] = mask[v * NQ + q0 + qq];
        cxy_s[qq][v] = coords[v * NQ + q0 + qq];
    }
    if (t < SQB * 128) {
        int qq = t >> 7, c2 = t & 127;
        aw_s[qq][c2] = aw[(size_t)(q0 + qq) * 128 + c2];
    }
    __syncthreads();

    const int LW[4] = {100, 50, 25, 13};
    const int LH[4] = {56, 28, 14, 7};
    for (int idx = t; idx < SQB * NV * 128; idx += 256) {
        int c2 = idx & 127;
        int rem = idx >> 7;
        int qq = rem / NV, v = rem - qq * NV;
        if (msk_s[qq][v]) {
            int ll = (c2 >> 2) & 3;
            float wl = (float)LW[ll], hl = (float)LH[ll];
            float2 o2 = *(const float2*)&off[(size_t)(q0 + qq) * 256 + 2 * c2];
            float2 cc = cxy_s[qq][v];
            float gx = cc.x * wl + o2.x - 0.5f;
            float gy = cc.y * hl + o2.y - 0.5f;
            float fx = floorf(gx), fy = floorf(gy);
            int x0 = (int)fx, y0 = (int)fy;
            pxy_s[qq][v][c2] = (x0 & 0xFFFF) | (y0 << 16);
            wxy_s[qq][v][c2] = make_float2(gx - fx, gy - fy);
        }
    }
    __syncthreads();

    int h = t >> 5;
#pragma unroll
    for (int qq = 0; qq < SQB; ++qq) {
        float acc = 0.0f;
        int cnt = 0;
#pragma unroll
        for (int v = 0; v < NV; ++v) cnt += msk_s[qq][v];
        for (int v = 0; v < NV; ++v) {
            if (!msk_s[qq][v]) continue;
            const unsigned short* vb = value + (size_t)v * NTOK * 256 + t;
#pragma unroll
            for (int ci = 0; ci < 16; ++ci) {
                int c2 = h * 16 + ci;
                int ll = ci >> 2;
                int wl = LW[ll], hl = LH[ll];
                int st = (ll == 0) ? 0 : (ll == 1) ? 5600 : (ll == 2) ? 7000 : 7350;
                int p = pxy_s[qq][v][c2];
                int x0 = (int)(short)(p & 0xFFFF);
                int y0 = p >> 16;
                float2 wxy = wxy_s[qq][v][c2];
                float wav = aw_s[qq][c2];
                bool bx0 = (unsigned)x0 < (unsigned)wl;
                bool bx1 = (unsigned)(x0 + 1) < (unsigned)wl;
                bool by0 = (unsigned)y0 < (unsigned)hl;
                bool by1 = (unsigned)(y0 + 1) < (unsigned)hl;
                int cx0 = min(max(x0, 0), wl - 1);
                int cx1 = min(max(x0 + 1, 0), wl - 1);
                int cy0 = min(max(y0, 0), hl - 1);
                int cy1 = min(max(y0 + 1, 0), hl - 1);
                int r0 = st + cy0 * wl, r1 = st + cy1 * wl;
                float s00 = bf2f(vb[(size_t)(r0 + cx0) * 256]);
                float s01 = bf2f(vb[(size_t)(r0 + cx1) * 256]);
                float s10 = bf2f(vb[(size_t)(r1 + cx0) * 256]);
                float s11 = bf2f(vb[(size_t)(r1 + cx1) * 256]);
                float ox = 1.0f - wxy.x, oy = 1.0f - wxy.y;
                float w00 = (bx0 && by0) ? ox * oy : 0.0f;
                float w01 = (bx1 && by0) ? wxy.x * oy : 0.0f;
                float w10 = (bx0 && by1) ? ox * wxy.y : 0.0f;
                float w11 = (bx1 && by1) ? wxy.x * wxy.y : 0.0f;
                acc += wav * (w00 * s00 + w01 * s01 + w10 * s10 + w11 * s11);
            }
        }
        slots[(size_t)(q0 + qq) * 256 + t] = acc / fmaxf((float)cnt, 1.0f);
    }
}

// ---------------------------------------------------------------------------
extern "C" void kernel_launch(void* const* d_in, const int* in_sizes, int n_in,
                              void* d_out, int out_size, void* d_ws, size_t ws_size,
                              hipStream_t stream) {
    const float* f0   = (const float*)d_in[0];
    const float* f1   = (const float*)d_in[1];
    const float* f2   = (const float*)d_in[2];
    const float* f3   = (const float*)d_in[3];
    const float* l2i  = (const float*)d_in[4];
    const float* bev  = (const float*)d_in[5];
    const float* le   = (const float*)d_in[6];
    const float* ve   = (const float*)d_in[7];
    const float* vW   = (const float*)d_in[8];
    const float* vB   = (const float*)d_in[9];
    const float* oW   = (const float*)d_in[10];
    const float* oB   = (const float*)d_in[11];
    const float* aW   = (const float*)d_in[12];
    const float* aB   = (const float*)d_in[13];
    const float* outW = (const float*)d_in[14];
    const float* outB = (const float*)d_in[15];
    float* out = (float*)d_out;

    char* ws = (char*)d_ws;
    size_t o = 0;
    auto alloc = [&](size_t bytes) {
        void* p = ws + o;
        o += (bytes + 255) & ~(size_t)255;
        return p;
    };
    float2* coords   = (float2*)alloc((size_t)NV * NQ * sizeof(float2));
    int*    mask     = (int*)alloc((size_t)NV * NQ * sizeof(int));
    float*  emb_proj = (float*)alloc((size_t)24 * ND * sizeof(float));
    float*  off      = (float*)alloc((size_t)NQ * 256 * sizeof(float));
    float*  aw_pre   = (float*)alloc((size_t)NQ * 128 * sizeof(float));
    float*  aw       = (float*)alloc((size_t)NQ * 128 * sizeof(float));
    float*  slots    = (float*)alloc((size_t)NQ * 256 * sizeof(float));
    unsigned short* value = (unsigned short*)alloc((size_t)MROWS * ND * sizeof(short));
    unsigned short* vWt   = (unsigned short*)alloc((size_t)256 * 256 * sizeof(short));
    unsigned short* oWt   = (unsigned short*)alloc((size_t)256 * 256 * sizeof(short));
    unsigned short* aWt   = (unsigned short*)alloc((size_t)128 * 256 * sizeof(short));
    unsigned short* outWt = (unsigned short*)alloc((size_t)256 * 256 * sizeof(short));

    k_proj<<<(NV * NQ + 255) / 256, 256, 0, stream>>>(l2i, coords, mask);
    k_embproj<<<24, 256, 0, stream>>>(ve, le, vW, vB, emb_proj);
    k_transpose<<<(256 * 256 + 255) / 256, 256, 0, stream>>>(vW, vWt, 256);
    k_transpose<<<(256 * 256 + 255) / 256, 256, 0, stream>>>(oW, oWt, 256);
    k_transpose<<<(128 * 256 + 255) / 256, 256, 0, stream>>>(aW, aWt, 128);
    k_transpose<<<(256 * 256 + 255) / 256, 256, 0, stream>>>(outW, outWt, 256);

    dim3 goff(NQ / 128, 2);
    k_gemm<<<goff, 256, 0, stream>>>(bev, 256, oWt, oB, nullptr, off, 256);
    dim3 gaw(NQ / 128, 1);
    k_gemm<<<gaw, 256, 0, stream>>>(bev, 256, aWt, aB, nullptr, aw_pre, 128);
    k_softmax<<<(NQ * NHEAD + 255) / 256, 256, 0, stream>>>(aw_pre, aw);

    dim3 gv((MROWS + 127) / 128, 2);
    k_value_gemm<<<gv, 256, 0, stream>>>(f0, f1, f2, f3, vWt, emb_proj, value);

    k_sample<<<NQ / SQB, 256, 0, stream>>>(coords, mask, off, aw, value, slots);

    dim3 gout(NQ / 128, 2);
    k_gemm<<<gout, 256, 0, stream>>>(slots, 256, outWt, outB, bev, out, 256);
}

// Round 3
// 199.634 us; speedup vs baseline: 1.7431x; 1.2545x over previous
//
#include <hip/hip_runtime.h>
#include <cstdint>
#include <cstddef>

#define NV 6
#define ND 256
#define NHEAD 8
#define NBEV 80
#define NQ 6400
#define NTOK 7441
#define MROWS (NV * NTOK)
#define FEPS 1e-5f

typedef __attribute__((ext_vector_type(8))) short bfx8;
typedef __attribute__((ext_vector_type(4))) float fx4;

__device__ __forceinline__ unsigned short f2bf(float x) {
    uint32_t u = __builtin_bit_cast(uint32_t, x);
    u += 0x7FFFu + ((u >> 16) & 1u);
    return (unsigned short)(u >> 16);
}
__device__ __forceinline__ float lof(uint32_t u) {
    return __builtin_bit_cast(float, u << 16);
}
__device__ __forceinline__ float hif(uint32_t u) {
    return __builtin_bit_cast(float, u & 0xFFFF0000u);
}

// ---------------------------------------------------------------------------
// K_prep (flat grid, 1070 blocks x 256):
//   [0,150)      proj: coords/mask per (v,q)  (ZP collapse; ref z-bug faithful)
//   [150,406)    vWt  = bf16(vW^T)            [256][256]
//   [406,662)    oaWt rows 0..255 from oW     [384][256] concat
//   [662,790)    oaWt rows 256..383 from aW
//   [790,1046)   outWt = bf16(outW^T)
//   [1046,1070)  emb_proj[v*4+l][c] = (ve[v]+le[l]) @ vW + vB  (f32)
// ---------------------------------------------------------------------------
__global__ __launch_bounds__(256) void k_prep(
        const float* __restrict__ l2i, const float* __restrict__ ve,
        const float* __restrict__ le, const float* __restrict__ vW,
        const float* __restrict__ vB, const float* __restrict__ oW,
        const float* __restrict__ aW, const float* __restrict__ outW,
        float2* __restrict__ coords, int* __restrict__ mask,
        unsigned short* __restrict__ vWt, unsigned short* __restrict__ oaWt,
        unsigned short* __restrict__ outWt, float* __restrict__ emb_proj) {
    int bid = blockIdx.x;
    int t = threadIdx.x;
    if (bid < 150) {
        int idx = bid * 256 + t;
        int v = idx / NQ, q = idx - v * NQ;
        float xs = ((float)(q % NBEV) + 0.5f) / (float)NBEV;
        float ys = ((float)(q / NBEV) + 0.5f) / (float)NBEV;
        float x = xs * 96.0f - 48.0f;
        float y = ys * 96.0f - 48.0f;
        float z = x * 8.0f - 5.0f;  // faithful ref bug
        const float* M = l2i + v * 16;
        float ip0 = M[0] * x + M[1] * y + M[2] * z + M[3];
        float ip1 = M[4] * x + M[5] * y + M[6] * z + M[7];
        float ip2 = M[8] * x + M[9] * y + M[10] * z + M[11];
        float dz = fmaxf(ip2, FEPS);
        float xn = ip0 / dz / 800.0f;
        float yn = ip1 / dz / 448.0f;
        bool m = (ip2 > FEPS) && (xn > 0.0f) && (xn < 1.0f) && (yn > 0.0f) && (yn < 1.0f);
        coords[idx] = make_float2(xn, yn);
        mask[idx] = m ? 1 : 0;
    } else if (bid < 406) {
        int e = (bid - 150) * 256 + t;
        int n = e >> 8, k = e & 255;
        vWt[(size_t)n * 256 + k] = f2bf(vW[(size_t)k * 256 + n]);
    } else if (bid < 662) {
        int e = (bid - 406) * 256 + t;
        int n = e >> 8, k = e & 255;
        oaWt[(size_t)n * 256 + k] = f2bf(oW[(size_t)k * 256 + n]);
    } else if (bid < 790) {
        int e = (bid - 662) * 256 + t;
        int n = e >> 8, k = e & 255;
        oaWt[(size_t)(256 + n) * 256 + k] = f2bf(aW[(size_t)k * 128 + n]);
    } else if (bid < 1046) {
        int e = (bid - 790) * 256 + t;
        int n = e >> 8, k = e & 255;
        outWt[(size_t)n * 256 + k] = f2bf(outW[(size_t)k * 256 + n]);
    } else {
        int blk = bid - 1046;  // v*4 + l
        int v = blk >> 2, l = blk & 3;
        float acc = vB[t];
        for (int d = 0; d < ND; ++d)
            acc += (ve[v * ND + d] + le[l * ND + d]) * vW[d * ND + t];
        emb_proj[blk * ND + t] = acc;
    }
}

// ---------------------------------------------------------------------------
// K_gemms (flat grid 848): blocks [0,698) = value GEMM (gathered A, bf16 out,
// emb_proj epilogue); blocks [698,848) = [off|aw] GEMM (A=bev, N=384 concat).
// Tile 128x128, 4 waves (2x2), 4x4 frags of 16x16x32 bf16 MFMA.
// ---------------------------------------------------------------------------
__global__ __launch_bounds__(256) void k_gemms(
        const float* __restrict__ f0, const float* __restrict__ f1,
        const float* __restrict__ f2, const float* __restrict__ f3,
        const unsigned short* __restrict__ vWt, const float* __restrict__ emb_proj,
        unsigned short* __restrict__ value,
        const float* __restrict__ bev, const unsigned short* __restrict__ oaWt,
        const float* __restrict__ oB, const float* __restrict__ aB,
        float* __restrict__ off, float* __restrict__ aw_pre) {
    __shared__ unsigned short As[128][40];
    __shared__ unsigned short Bs[128][40];
    __shared__ const float* rowptr[128];
    __shared__ int rowstride[128];
    __shared__ int rowemb[128];
    int bid = blockIdx.x;
    int t = threadIdx.x;
    int lane = t & 63, w = t >> 6;
    int wm = w >> 1, wn = w & 1;
    int lr = lane & 15, lk = lane >> 4;

    fx4 acc[4][4];
#pragma unroll
    for (int i = 0; i < 4; ++i)
#pragma unroll
        for (int j = 0; j < 4; ++j) acc[i][j] = (fx4)0.0f;

    if (bid < 698) {
        // ---------------- value GEMM ----------------
        int m0 = (bid >> 1) * 128, c0 = (bid & 1) * 128;
        if (t < 128) {
            int m = m0 + t;
            if (m >= MROWS) m = MROWS - 1;
            int v = m / NTOK, n = m - v * NTOK;
            int l, p, hw;
            const float* base;
            if (n < 5600)      { l = 0; p = n;        hw = 5600; base = f0; }
            else if (n < 7000) { l = 1; p = n - 5600; hw = 1400; base = f1; }
            else if (n < 7350) { l = 2; p = n - 7000; hw = 350;  base = f2; }
            else               { l = 3; p = n - 7350; hw = 91;   base = f3; }
            rowptr[t] = base + (size_t)v * ND * hw + p;
            rowstride[t] = hw;
            rowemb[t] = v * 4 + l;
        }
        __syncthreads();
        int mA = t & 127, kg = t >> 7;
        const unsigned short* bp = vWt + (size_t)(c0 + (t >> 1)) * 256 + (t & 1) * 16;
        int br = t >> 1, bc = (t & 1) * 16;
        const float* rp = rowptr[mA];
        int rs = rowstride[mA];
        for (int k0 = 0; k0 < 256; k0 += 32) {
            float va[16];
#pragma unroll
            for (int i = 0; i < 16; ++i)
                va[i] = rp[(size_t)(k0 + kg * 16 + i) * rs];
            bfx8 lo8, hi8;
#pragma unroll
            for (int i = 0; i < 8; ++i) {
                lo8[i] = (short)f2bf(va[i]);
                hi8[i] = (short)f2bf(va[i + 8]);
            }
            *(bfx8*)&As[mA][kg * 16] = lo8;
            *(bfx8*)&As[mA][kg * 16 + 8] = hi8;
            *(bfx8*)&Bs[br][bc] = *(const bfx8*)(bp + k0);
            *(bfx8*)&Bs[br][bc + 8] = *(const bfx8*)(bp + k0 + 8);
            __syncthreads();
            bfx8 af[4], bf[4];
#pragma unroll
            for (int f = 0; f < 4; ++f) {
                af[f] = *(bfx8*)&As[wm * 64 + f * 16 + lr][lk * 8];
                bf[f] = *(bfx8*)&Bs[wn * 64 + f * 16 + lr][lk * 8];
            }
#pragma unroll
            for (int fm = 0; fm < 4; ++fm)
#pragma unroll
                for (int fn = 0; fn < 4; ++fn)
                    acc[fm][fn] = __builtin_amdgcn_mfma_f32_16x16x32_bf16(
                        af[fm], bf[fn], acc[fm][fn], 0, 0, 0);
            __syncthreads();
        }
#pragma unroll
        for (int fm = 0; fm < 4; ++fm) {
#pragma unroll
            for (int fn = 0; fn < 4; ++fn) {
                int col = c0 + wn * 64 + fn * 16 + lr;
#pragma unroll
                for (int r = 0; r < 4; ++r) {
                    int rl = wm * 64 + fm * 16 + lk * 4 + r;
                    int m = m0 + rl;
                    if (m < MROWS) {
                        float e = emb_proj[(size_t)rowemb[rl] * ND + col];
                        value[(size_t)m * ND + col] = f2bf(acc[fm][fn][r] + e);
                    }
                }
            }
        }
    } else {
        // ---------------- off/aw GEMM ----------------
        int r6 = bid - 698;                 // 50 x 3
        int m0 = (r6 / 3) * 128, c0 = (r6 % 3) * 128;
        const float* ap = bev + (size_t)(m0 + (t >> 1)) * 256 + (t & 1) * 16;
        const unsigned short* bp = oaWt + (size_t)(c0 + (t >> 1)) * 256 + (t & 1) * 16;
        int sr = t >> 1, sc = (t & 1) * 16;
        for (int k0 = 0; k0 < 256; k0 += 32) {
            float va[16];
#pragma unroll
            for (int i = 0; i < 4; ++i)
                *(float4*)&va[i * 4] = *(const float4*)(ap + k0 + i * 4);
            bfx8 lo8, hi8;
#pragma unroll
            for (int i = 0; i < 8; ++i) {
                lo8[i] = (short)f2bf(va[i]);
                hi8[i] = (short)f2bf(va[i + 8]);
            }
            *(bfx8*)&As[sr][sc] = lo8;
            *(bfx8*)&As[sr][sc + 8] = hi8;
            *(bfx8*)&Bs[sr][sc] = *(const bfx8*)(bp + k0);
            *(bfx8*)&Bs[sr][sc + 8] = *(const bfx8*)(bp + k0 + 8);
            __syncthreads();
            bfx8 af[4], bf[4];
#pragma unroll
            for (int f = 0; f < 4; ++f) {
                af[f] = *(bfx8*)&As[wm * 64 + f * 16 + lr][lk * 8];
                bf[f] = *(bfx8*)&Bs[wn * 64 + f * 16 + lr][lk * 8];
            }
#pragma unroll
            for (int fm = 0; fm < 4; ++fm)
#pragma unroll
                for (int fn = 0; fn < 4; ++fn)
                    acc[fm][fn] = __builtin_amdgcn_mfma_f32_16x16x32_bf16(
                        af[fm], bf[fn], acc[fm][fn], 0, 0, 0);
            __syncthreads();
        }
        if (c0 < 256) {
#pragma unroll
            for (int fm = 0; fm < 4; ++fm) {
#pragma unroll
                for (int fn = 0; fn < 4; ++fn) {
                    int col = c0 + wn * 64 + fn * 16 + lr;
                    float bs = oB[col];
#pragma unroll
                    for (int r = 0; r < 4; ++r) {
                        int m = m0 + wm * 64 + fm * 16 + lk * 4 + r;
                        off[(size_t)m * 256 + col] = acc[fm][fn][r] + bs;
                    }
                }
            }
        } else {
#pragma unroll
            for (int fm = 0; fm < 4; ++fm) {
#pragma unroll
                for (int fn = 0; fn < 4; ++fn) {
                    int col = wn * 64 + fn * 16 + lr;  // 0..127 within aw
                    float bs = aB[col];
#pragma unroll
                    for (int r = 0; r < 4; ++r) {
                        int m = m0 + wm * 64 + fm * 16 + lk * 4 + r;
                        aw_pre[(size_t)m * 128 + col] = acc[fm][fn][r] + bs;
                    }
                }
            }
        }
    }
}

// ---------------------------------------------------------------------------
// K_sample: 2 queries/block, thread = (qq, channel-pair). Prologue computes
// softmax(aw) + per-(q,v,combo) clamped indices & aw-premultiplied weights
// once into LDS; main loop = 2 LDS b128 broadcasts + 4 coalesced uint loads
// + 8 FMA per (v,combo). XCD-chunked block swizzle for L2 locality.
// ---------------------------------------------------------------------------
#define SQB 2
__global__ __launch_bounds__(256) void k_sample(
        const float2* __restrict__ coords, const int* __restrict__ mask,
        const float* __restrict__ off, const float* __restrict__ awlog,
        const unsigned short* __restrict__ value, float* __restrict__ slots) {
    __shared__ float aw_s[SQB][128];
    __shared__ int  lin_s[SQB][NV][128][4];
    __shared__ float w_s[SQB][NV][128][4];
    __shared__ float2 cxy_s[SQB][NV];
    __shared__ int msk_s[SQB][NV];

    int b = blockIdx.x;                      // 3200, % 8 == 0
    int lb = (b & 7) * (NQ / SQB / 8) + (b >> 3);
    int q0 = lb * SQB;
    int t = threadIdx.x;
    if (t < SQB * NV) {
        int qq = t / NV, v = t - qq * NV;
        msk_s[qq][v] = mask[v * NQ + q0 + qq];
        cxy_s[qq][v] = coords[v * NQ + q0 + qq];
    }
    {
        int qq = t >> 7, c2 = t & 127;
        aw_s[qq][c2] = awlog[(size_t)(q0 + qq) * 128 + c2];
    }
    __syncthreads();
    if (t < SQB * NHEAD) {
        int qq = t >> 3, h = t & 7;
        float* p = &aw_s[qq][h * 16];
        float mx = p[0];
#pragma unroll
        for (int i = 1; i < 16; ++i) mx = fmaxf(mx, p[i]);
        float e[16];
        float s = 0.0f;
#pragma unroll
        for (int i = 0; i < 16; ++i) { e[i] = __expf(p[i] - mx); s += e[i]; }
        float inv = 1.0f / s;
#pragma unroll
        for (int i = 0; i < 16; ++i) p[i] = e[i] * inv;
    }
    __syncthreads();

    const int LW[4] = {100, 50, 25, 13};
    const int LH[4] = {56, 28, 14, 7};
    const int LST[4] = {0, 5600, 7000, 7350};
    for (int idx = t; idx < SQB * NV * 128; idx += 256) {
        int c2 = idx & 127;
        int rem = idx >> 7;
        int qq = rem / NV, v = rem - qq * NV;
        if (!msk_s[qq][v]) continue;
        int ll = (c2 >> 2) & 3;
        int iwl = LW[ll], ihl = LH[ll], st = LST[ll];
        float wl = (float)iwl, hl = (float)ihl;
        float2 o2 = *(const float2*)&off[(size_t)(q0 + qq) * 256 + 2 * c2];
        float2 cc = cxy_s[qq][v];
        float gx = cc.x * wl + o2.x - 0.5f;
        float gy = cc.y * hl + o2.y - 0.5f;
        float fxf = floorf(gx), fyf = floorf(gy);
        int x0 = (int)fxf, y0 = (int)fyf;
        float wx = gx - fxf, wy = gy - fyf;
        bool bx0 = (unsigned)x0 < (unsigned)iwl;
        bool bx1 = (unsigned)(x0 + 1) < (unsigned)iwl;
        bool by0 = (unsigned)y0 < (unsigned)ihl;
        bool by1 = (unsigned)(y0 + 1) < (unsigned)ihl;
        int cx0 = min(max(x0, 0), iwl - 1);
        int cx1 = min(max(x0 + 1, 0), iwl - 1);
        int cy0 = min(max(y0, 0), ihl - 1);
        int cy1 = min(max(y0 + 1, 0), ihl - 1);
        float wa = aw_s[qq][c2];
        int r0 = st + cy0 * iwl, r1 = st + cy1 * iwl;
        lin_s[qq][v][c2][0] = r0 + cx0;
        lin_s[qq][v][c2][1] = r0 + cx1;
        lin_s[qq][v][c2][2] = r1 + cx0;
        lin_s[qq][v][c2][3] = r1 + cx1;
        w_s[qq][v][c2][0] = (bx0 && by0) ? (1.0f - wx) * (1.0f - wy) * wa : 0.0f;
        w_s[qq][v][c2][1] = (bx1 && by0) ? wx * (1.0f - wy) * wa : 0.0f;
        w_s[qq][v][c2][2] = (bx0 && by1) ? (1.0f - wx) * wy * wa : 0.0f;
        w_s[qq][v][c2][3] = (bx1 && by1) ? wx * wy * wa : 0.0f;
    }
    __syncthreads();

    int qq = t >> 7, cp = t & 127;
    int hb = (cp >> 4) * 16;
    float acc0 = 0.0f, acc1 = 0.0f;
    int cnt = 0;
#pragma unroll
    for (int v = 0; v < NV; ++v) cnt += msk_s[qq][v];
    for (int v = 0; v < NV; ++v) {
        if (!msk_s[qq][v]) continue;
        const uint32_t* vb = (const uint32_t*)(value + (size_t)v * NTOK * 256) + cp;
#pragma unroll
        for (int ci = 0; ci < 16; ++ci) {
            int c2 = hb + ci;
            int4 lin = *(const int4*)lin_s[qq][v][c2];
            float4 ww = *(const float4*)w_s[qq][v][c2];
            uint32_t u0 = vb[(size_t)lin.x * 128];
            uint32_t u1 = vb[(size_t)lin.y * 128];
            uint32_t u2 = vb[(size_t)lin.z * 128];
            uint32_t u3 = vb[(size_t)lin.w * 128];
            acc0 += ww.x * lof(u0) + ww.y * lof(u1) + ww.z * lof(u2) + ww.w * lof(u3);
            acc1 += ww.x * hif(u0) + ww.y * hif(u1) + ww.z * hif(u2) + ww.w * hif(u3);
        }
    }
    float invc = 1.0f / fmaxf((float)cnt, 1.0f);
    *(float2*)&slots[(size_t)(q0 + qq) * 256 + 2 * cp] = make_float2(acc0 * invc, acc1 * invc);
}

// ---------------------------------------------------------------------------
// K_out: out = slots @ outWt^T + outB + bev   (128x128 MFMA tile)
// ---------------------------------------------------------------------------
__global__ __launch_bounds__(256) void k_out(
        const float* __restrict__ A, const unsigned short* __restrict__ Bt,
        const float* __restrict__ bias, const float* __restrict__ addsrc,
        float* __restrict__ out) {
    __shared__ unsigned short As[128][40];
    __shared__ unsigned short Bs[128][40];
    int t = threadIdx.x;
    int m0 = blockIdx.x * 128, c0 = blockIdx.y * 128;
    int lane = t & 63, w = t >> 6;
    int wm = w >> 1, wn = w & 1;
    int lr = lane & 15, lk = lane >> 4;
    const float* ap = A + (size_t)(m0 + (t >> 1)) * 256 + (t & 1) * 16;
    const unsigned short* bp = Bt + (size_t)(c0 + (t >> 1)) * 256 + (t & 1) * 16;
    int sr = t >> 1, sc = (t & 1) * 16;
    fx4 acc[4][4];
#pragma unroll
    for (int i = 0; i < 4; ++i)
#pragma unroll
        for (int j = 0; j < 4; ++j) acc[i][j] = (fx4)0.0f;
    for (int k0 = 0; k0 < 256; k0 += 32) {
        float va[16];
#pragma unroll
        for (int i = 0; i < 4; ++i)
            *(float4*)&va[i * 4] = *(const float4*)(ap + k0 + i * 4);
        bfx8 lo8, hi8;
#pragma unroll
        for (int i = 0; i < 8; ++i) {
            lo8[i] = (short)f2bf(va[i]);
            hi8[i] = (short)f2bf(va[i + 8]);
        }
        *(bfx8*)&As[sr][sc] = lo8;
        *(bfx8*)&As[sr][sc + 8] = hi8;
        *(bfx8*)&Bs[sr][sc] = *(const bfx8*)(bp + k0);
        *(bfx8*)&Bs[sr][sc + 8] = *(const bfx8*)(bp + k0 + 8);
        __syncthreads();
        bfx8 af[4], bf[4];
#pragma unroll
        for (int f = 0; f < 4; ++f) {
            af[f] = *(bfx8*)&As[wm * 64 + f * 16 + lr][lk * 8];
            bf[f] = *(bfx8*)&Bs[wn * 64 + f * 16 + lr][lk * 8];
        }
#pragma unroll
        for (int fm = 0; fm < 4; ++fm)
#pragma unroll
            for (int fn = 0; fn < 4; ++fn)
                acc[fm][fn] = __builtin_amdgcn_mfma_f32_16x16x32_bf16(
                    af[fm], bf[fn], acc[fm][fn], 0, 0, 0);
        __syncthreads();
    }
#pragma unroll
    for (int fm = 0; fm < 4; ++fm) {
#pragma unroll
        for (int fn = 0; fn < 4; ++fn) {
            int col = c0 + wn * 64 + fn * 16 + lr;
            float bs = bias[col];
#pragma unroll
            for (int r = 0; r < 4; ++r) {
                int m = m0 + wm * 64 + fm * 16 + lk * 4 + r;
                out[(size_t)m * 256 + col] =
                    acc[fm][fn][r] + bs + addsrc[(size_t)m * 256 + col];
            }
        }
    }
}

// ---------------------------------------------------------------------------
extern "C" void kernel_launch(void* const* d_in, const int* in_sizes, int n_in,
                              void* d_out, int out_size, void* d_ws, size_t ws_size,
                              hipStream_t stream) {
    const float* f0   = (const float*)d_in[0];
    const float* f1   = (const float*)d_in[1];
    const float* f2   = (const float*)d_in[2];
    const float* f3   = (const float*)d_in[3];
    const float* l2i  = (const float*)d_in[4];
    const float* bev  = (const float*)d_in[5];
    const float* le   = (const float*)d_in[6];
    const float* ve   = (const float*)d_in[7];
    const float* vW   = (const float*)d_in[8];
    const float* vB   = (const float*)d_in[9];
    const float* oW   = (const float*)d_in[10];
    const float* oB   = (const float*)d_in[11];
    const float* aW   = (const float*)d_in[12];
    const float* aB   = (const float*)d_in[13];
    const float* outW = (const float*)d_in[14];
    const float* outB = (const float*)d_in[15];
    float* out = (float*)d_out;

    char* ws = (char*)d_ws;
    size_t o = 0;
    auto alloc = [&](size_t bytes) {
        void* p = ws + o;
        o += (bytes + 255) & ~(size_t)255;
        return p;
    };
    float2* coords   = (float2*)alloc((size_t)NV * NQ * sizeof(float2));
    int*    mask     = (int*)alloc((size_t)NV * NQ * sizeof(int));
    float*  emb_proj = (float*)alloc((size_t)24 * ND * sizeof(float));
    float*  off      = (float*)alloc((size_t)NQ * 256 * sizeof(float));
    float*  aw_pre   = (float*)alloc((size_t)NQ * 128 * sizeof(float));
    float*  slots    = (float*)alloc((size_t)NQ * 256 * sizeof(float));
    unsigned short* value = (unsigned short*)alloc((size_t)MROWS * ND * sizeof(short));
    unsigned short* vWt   = (unsigned short*)alloc((size_t)256 * 256 * sizeof(short));
    unsigned short* oaWt  = (unsigned short*)alloc((size_t)384 * 256 * sizeof(short));
    unsigned short* outWt = (unsigned short*)alloc((size_t)256 * 256 * sizeof(short));

    k_prep<<<1070, 256, 0, stream>>>(l2i, ve, le, vW, vB, oW, aW, outW,
                                     coords, mask, vWt, oaWt, outWt, emb_proj);
    k_gemms<<<848, 256, 0, stream>>>(f0, f1, f2, f3, vWt, emb_proj, value,
                                     bev, oaWt, oB, aB, off, aw_pre);
    k_sample<<<NQ / SQB, 256, 0, stream>>>(coords, mask, off, aw_pre, value, slots);
    dim3 gout(NQ / 128, 2);
    k_out<<<gout, 256, 0, stream>>>(slots, outWt, outB, bev, out);
}